// Round 1
// baseline (1898.241 us; speedup 1.0000x reference)
//
#include <hip/hip_runtime.h>
#include <math.h>

#define NN 10000
#define EE 100000
#define NE 16
#define RS 876

// staged-input offsets (floats within a row)
#define IN0 0
#define XP1 288
#define XM1 480
#define XP2 672
#define XM2 768
// reuse region (after GEMM barrier)
#define Y0o   0
#define Y10o  96
#define Y20o  128
#define Y1Po  160
#define Y1Mo  192
#define Y2P1o 224
#define Y2M1o 256
#define Y2P2o 288
#define Y2M2o 320
#define WENVo 352
#define SCALo 448
#define M1Go  480
#define M2Go  576

#define SQ3F  1.7320508075688772f
#define S0F   0.05892556509887896f   // 1/sqrt(288)
#define S1F   0.07216878364870323f   // 1/sqrt(192)
#define S2F   0.10206207261596575f   // 1/sqrt(96)
#define SEF   0.08838834764831845f   // 1/sqrt(128)
#define SCF   0.17677669529663687f   // 1/sqrt(32)
#define COLDF 0.8944271909999159f    // 1/sqrt(1.25)
#define COEFF 0.1414213562373095f    // 0.5/sqrt(1.25)/sqrt(10)

__device__ __forceinline__ float4 ld4(const float* p) { return *reinterpret_cast<const float4*>(p); }
__device__ __forceinline__ float dot4(const float4& a, const float4& b) {
    return a.x*b.x + a.y*b.y + a.z*b.z + a.w*b.w;
}

__global__ __launch_bounds__(256) void node_norm_k(
    const float* __restrict__ nf,
    const float* __restrict__ g0, const float* __restrict__ b0,
    const float* __restrict__ g1, const float* __restrict__ g2,
    float* __restrict__ nrm, float* __restrict__ out)
{
    int row = blockIdx.x * 4 + (threadIdx.x >> 6);
    if (row >= NN) return;
    int lane = threadIdx.x & 63;
    const float* r = nf + (size_t)row * 288;
    float v0 = r[lane];
    float v1 = r[lane + 64];
    float v2 = r[lane + 128];
    float v3 = r[lane + 192];
    float v4 = (lane < 32) ? r[lane + 256] : 0.f;
    float s0 = 0.f, s0q = 0.f, q1 = 0.f, q2 = 0.f;
    if (lane < 32) { s0 = v0; s0q = v0*v0; } else { q1 = v0*v0; }
    q1 += v1*v1;
    q2 += v2*v2 + v3*v3 + v4*v4;
#pragma unroll
    for (int m = 1; m < 64; m <<= 1) {
        s0  += __shfl_xor(s0, m);
        s0q += __shfl_xor(s0q, m);
        q1  += __shfl_xor(q1, m);
        q2  += __shfl_xor(q2, m);
    }
    float mu  = s0 * (1.f/32.f);
    float var = s0q * (1.f/32.f) - mu*mu;
    float rs0 = rsqrtf(var + 1e-8f);
    float rv  = 0.5f * (q1 * (1.f/96.f) + q2 * (1.f/160.f));
    float rs  = rsqrtf(rv + 1e-8f);
    float* nr = nrm + (size_t)row * 288;
    float* orow = out + (size_t)row * 288;
    {
        float res;
        if (lane < 32) res = (v0 - mu) * rs0 * g0[lane] + b0[lane];
        else { int c = (lane - 32) / 3; res = v0 * rs * g1[c]; }
        nr[lane] = res; orow[lane] = COLDF * v0;
    }
    { int k = lane + 64;  int c = (k - 32) / 3;  nr[k] = v1 * rs * g1[c]; orow[k] = COLDF * v1; }
    { int k = lane + 128; int c = (k - 128) / 5; nr[k] = v2 * rs * g2[c]; orow[k] = COLDF * v2; }
    { int k = lane + 192; int c = (k - 128) / 5; nr[k] = v3 * rs * g2[c]; orow[k] = COLDF * v3; }
    if (lane < 32) { int k = lane + 256; int c = (k - 128) / 5; nr[k] = v4 * rs * g2[c]; orow[k] = COLDF * v4; }
}

__global__ __launch_bounds__(256) void edge_k(
    const float* __restrict__ lat, const float* __restrict__ ef,
    const float* __restrict__ evec,
    const int* __restrict__ eidx, const int* __restrict__ act,
    const float* __restrict__ g0e, const float* __restrict__ b0e,
    const float* __restrict__ g1e, const float* __restrict__ g2e,
    const float* __restrict__ w0s, const float* __restrict__ w01, const float* __restrict__ w02,
    const float* __restrict__ wr11, const float* __restrict__ wi11,
    const float* __restrict__ wr12, const float* __restrict__ wi12,
    const float* __restrict__ wr22, const float* __restrict__ wi22,
    const float* __restrict__ wp0, const float* __restrict__ bp0,
    const float* __restrict__ wp1, const float* __restrict__ wp2,
    const float* __restrict__ wenv, const float* __restrict__ benv,
    const float* __restrict__ nrm, float* __restrict__ out)
{
    __shared__ __align__(16) float sR[NE][RS];
    __shared__ float sD1[NE][12];
    __shared__ float sD2[NE][28];
    __shared__ int sCtr[NE];

    const int tid = threadIdx.x;
    const int wv = tid >> 6, lane = tid & 63;

    // ---------------- prep: wave per edge, 4 iterations ----------------
    for (int it = 0; it < 4; ++it) {
        const int e = it * 4 + wv;
        const int ge = blockIdx.x * NE + e;
        const int ae = act[ge];
        const int ctr = eidx[ae], nbr = eidx[EE + ae];
        if (lane == 0) sCtr[e] = ctr;

        // local frame D1 = rows (u, n, v)
        float vx = evec[3*ae], vy = evec[3*ae+1], vz = evec[3*ae+2];
        float nnv = fmaxf(sqrtf(vx*vx + vy*vy + vz*vz), 1e-9f);
        float nx = vx/nnv, ny = vy/nnv, nz = vz/nnv;
        float ax, az;
        if (fabsf(nx) < 0.9f) { ax = 1.f; az = 0.f; } else { ax = 0.f; az = 1.f; }
        float adn = ax*nx + az*nz;
        float ux = ax - adn*nx, uy = -adn*ny, uz = az - adn*nz;
        float un = fmaxf(sqrtf(ux*ux + uy*uy + uz*uz), 1e-9f);
        ux /= un; uy /= un; uz /= un;
        float wx = uy*nz - uz*ny, wy = uz*nx - ux*nz, wz = ux*ny - uy*nx;

        // analytic l=2 Wigner matrix of D1 (== reference's pinv construction exactly)
        float d2[5][5];
        d2[0][0] = wz*ux + uz*wx;  d2[0][1] = wx*uy + ux*wy;  d2[0][2] = SQ3F*wy*uy;
        d2[0][3] = wy*uz + uy*wz;  d2[0][4] = wz*uz - wx*ux;
        d2[1][0] = uz*nx + nz*ux;  d2[1][1] = ux*ny + nx*uy;  d2[1][2] = SQ3F*uy*ny;
        d2[1][3] = uy*nz + ny*uz;  d2[1][4] = uz*nz - ux*nx;
        d2[2][0] = SQ3F*nz*nx;     d2[2][1] = SQ3F*nx*ny;     d2[2][2] = 1.5f*ny*ny - 0.5f;
        d2[2][3] = SQ3F*ny*nz;     d2[2][4] = 0.5f*SQ3F*(nz*nz - nx*nx);
        d2[3][0] = nz*wx + wz*nx;  d2[3][1] = nx*wy + wx*ny;  d2[3][2] = SQ3F*ny*wy;
        d2[3][3] = ny*wz + wy*nz;  d2[3][4] = nz*wz - nx*wx;
        d2[4][0] = wz*wx - uz*ux;  d2[4][1] = wx*wy - ux*uy;  d2[4][2] = 0.5f*SQ3F*(wy*wy - uy*uy);
        d2[4][3] = wy*wz - uy*uz;  d2[4][4] = 0.5f*(wz*wz - uz*uz - wx*wx + ux*ux);

        // edge-feature SLN stats
        const float* efr = ef + (size_t)ae * 288;
        float ev0 = efr[lane];
        float ev1 = efr[lane + 64];
        float ev2 = efr[lane + 128];
        float ev3 = efr[lane + 192];
        float ev4 = (lane < 32) ? efr[lane + 256] : 0.f;
        float s0 = 0.f, s0q = 0.f, q1 = 0.f, q2 = 0.f;
        if (lane < 32) { s0 = ev0; s0q = ev0*ev0; } else { q1 = ev0*ev0; }
        q1 += ev1*ev1;
        q2 += ev2*ev2 + ev3*ev3 + ev4*ev4;
#pragma unroll
        for (int m = 1; m < 64; m <<= 1) {
            s0  += __shfl_xor(s0, m);
            s0q += __shfl_xor(s0q, m);
            q1  += __shfl_xor(q1, m);
            q2  += __shfl_xor(q2, m);
        }
        float mu  = s0 * (1.f/32.f);
        float rs0 = rsqrtf(s0q*(1.f/32.f) - mu*mu + 1e-8f);
        float rs  = rsqrtf(0.5f*(q1*(1.f/96.f) + q2*(1.f/160.f)) + 1e-8f);

        // scalar (l=0) concat part of in0
        if (lane < 32) {
            sR[e][IN0 + 32 + lane] = (ev0 - mu) * rs0 * g0e[lane] + b0e[lane];
            sR[e][IN0 + lane]      = nrm[(size_t)ctr*288 + lane];
            sR[e][IN0 + 64 + lane] = nrm[(size_t)nbr*288 + lane];
        }

        // rotate l=1/l=2 channels and scatter into staged layout
#pragma unroll
        for (int half = 0; half < 2; ++half) {
            const int cc = lane + 64*half;
            if (cc < 96) {
                float x1v[3], x2v[5];
                if (cc < 32) {
                    const float* b = nrm + (size_t)ctr * 288;
                    const int c = cc;
                    x1v[0] = b[32+3*c]; x1v[1] = b[33+3*c]; x1v[2] = b[34+3*c];
                    x2v[0] = b[128+5*c]; x2v[1] = b[129+5*c]; x2v[2] = b[130+5*c];
                    x2v[3] = b[131+5*c]; x2v[4] = b[132+5*c];
                } else if (cc < 64) {
                    const int c = cc - 32;
                    const float sa = rs * g1e[c], sb = rs * g2e[c];
                    x1v[0] = efr[32+3*c]*sa; x1v[1] = efr[33+3*c]*sa; x1v[2] = efr[34+3*c]*sa;
                    x2v[0] = efr[128+5*c]*sb; x2v[1] = efr[129+5*c]*sb; x2v[2] = efr[130+5*c]*sb;
                    x2v[3] = efr[131+5*c]*sb; x2v[4] = efr[132+5*c]*sb;
                } else {
                    const float* b = nrm + (size_t)nbr * 288;
                    const int c = cc - 64;
                    x1v[0] = b[32+3*c]; x1v[1] = b[33+3*c]; x1v[2] = b[34+3*c];
                    x2v[0] = b[128+5*c]; x2v[1] = b[129+5*c]; x2v[2] = b[130+5*c];
                    x2v[3] = b[131+5*c]; x2v[4] = b[132+5*c];
                }
                float r0 = ux*x1v[0] + uy*x1v[1] + uz*x1v[2];
                float r1 = nx*x1v[0] + ny*x1v[1] + nz*x1v[2];
                float r2 = wx*x1v[0] + wy*x1v[1] + wz*x1v[2];
                float t[5];
#pragma unroll
                for (int m = 0; m < 5; ++m)
                    t[m] = d2[m][0]*x2v[0] + d2[m][1]*x2v[1] + d2[m][2]*x2v[2]
                         + d2[m][3]*x2v[3] + d2[m][4]*x2v[4];
                sR[e][IN0 + 96  + cc] = r1;   // x1[:, :, 1]
                sR[e][IN0 + 192 + cc] = t[2]; // x2[:, :, 2]
                sR[e][XP1 + cc]       = r2;   // x1[:, :, 2]
                sR[e][XP1 + 96 + cc]  = t[3]; // x2[:, :, 3]
                sR[e][XM1 + cc]       = r0;   // x1[:, :, 0]
                sR[e][XM1 + 96 + cc]  = t[1]; // x2[:, :, 1]
                sR[e][XP2 + cc]       = t[4]; // x2[:, :, 4]
                sR[e][XM2 + cc]       = t[0]; // x2[:, :, 0]
            }
        }
        if (lane == 0) {
            sD1[e][0] = ux; sD1[e][1] = uy; sD1[e][2] = uz;
            sD1[e][3] = nx; sD1[e][4] = ny; sD1[e][5] = nz;
            sD1[e][6] = wx; sD1[e][7] = wy; sD1[e][8] = wz;
#pragma unroll
            for (int n = 0; n < 5; ++n)
#pragma unroll
                for (int m = 0; m < 5; ++m) sD2[e][5*n + m] = d2[n][m];
        }
    }
    __syncthreads();

    // ---------------- GEMM phase: thread = (edge, out-group) ----------------
    const int e2 = tid & 15, g = tid >> 4;
    const float* row = sR[e2];
    const int ae2 = act[blockIdx.x * NE + e2];

    float a0[10] = {};
    for (int k = 0; k < 288; k += 4) {
        float4 x = ld4(row + IN0 + k);
#pragma unroll
        for (int j = 0; j < 6; ++j) {
            float4 w = ld4(w0s + (g + 16*j)*288 + k);
            a0[j] += dot4(x, w);
        }
#pragma unroll
        for (int j = 0; j < 2; ++j) {
            float4 wa = ld4(w01 + (g + 16*j)*288 + k);
            a0[6+j] += dot4(x, wa);
            float4 wb = ld4(w02 + (g + 16*j)*288 + k);
            a0[8+j] += dot4(x, wb);
        }
    }
    float p1[2] = {}, m1a[2] = {}, p21[2] = {}, m21[2] = {};
    for (int k = 0; k < 192; k += 4) {
        float4 xp = ld4(row + XP1 + k);
        float4 xm = ld4(row + XM1 + k);
#pragma unroll
        for (int j = 0; j < 2; ++j) {
            const int o = g + 16*j;
            float4 wr = ld4(wr11 + o*192 + k);
            float4 wi = ld4(wi11 + o*192 + k);
            p1[j]  += dot4(xp, wr) - dot4(xm, wi);
            m1a[j] += dot4(xp, wi) + dot4(xm, wr);
            float4 wr2 = ld4(wr12 + o*192 + k);
            float4 wi2 = ld4(wi12 + o*192 + k);
            p21[j] += dot4(xp, wr2) - dot4(xm, wi2);
            m21[j] += dot4(xp, wi2) + dot4(xm, wr2);
        }
    }
    float p2[2] = {}, m2a[2] = {};
    for (int k = 0; k < 96; k += 4) {
        float4 xp = ld4(row + XP2 + k);
        float4 xm = ld4(row + XM2 + k);
#pragma unroll
        for (int j = 0; j < 2; ++j) {
            const int o = g + 16*j;
            float4 wr = ld4(wr22 + o*96 + k);
            float4 wi = ld4(wi22 + o*96 + k);
            p2[j]  += dot4(xp, wr) - dot4(xm, wi);
            m2a[j] += dot4(xp, wi) + dot4(xm, wr);
        }
    }
    float aE[6] = {};
    {
        const float* lr = lat + (size_t)ae2 * 128;
        for (int k = 0; k < 128; k += 4) {
            float4 x = ld4(lr + k);
#pragma unroll
            for (int j = 0; j < 6; ++j) {
                float4 w = ld4(wenv + (g + 16*j)*128 + k);
                aE[j] += dot4(x, w);
            }
        }
    }
    __syncthreads();

    // write intermediates into reused LDS row
#pragma unroll
    for (int j = 0; j < 6; ++j) sR[e2][Y0o + g + 16*j] = a0[j] * S0F;
#pragma unroll
    for (int j = 0; j < 2; ++j) {
        sR[e2][Y10o  + g + 16*j] = a0[6+j] * S0F;
        sR[e2][Y20o  + g + 16*j] = a0[8+j] * S0F;
        sR[e2][Y1Po  + g + 16*j] = p1[j]  * S1F;
        sR[e2][Y1Mo  + g + 16*j] = m1a[j] * S1F;
        sR[e2][Y2P1o + g + 16*j] = p21[j] * S1F;
        sR[e2][Y2M1o + g + 16*j] = m21[j] * S1F;
        sR[e2][Y2P2o + g + 16*j] = p2[j]  * S2F;
        sR[e2][Y2M2o + g + 16*j] = m2a[j] * S2F;
    }
#pragma unroll
    for (int j = 0; j < 6; ++j) {
        const int o = g + 16*j;
        sR[e2][WENVo + o] = aE[j] * SEF + benv[o];
    }
    __syncthreads();

    // ---------------- stage 2a: gates + rotate-back ----------------
#pragma unroll
    for (int ci = 0; ci < 2; ++ci) {
        const int c = g + 16*ci;
        float y0v = sR[e2][Y0o + c];
        float scv = y0v / (1.f + expf(-y0v));
        float gg1 = 1.f / (1.f + expf(-sR[e2][Y0o + 32 + c]));
        float gg2 = 1.f / (1.f + expf(-sR[e2][Y0o + 64 + c]));
        float y1n0 = sR[e2][Y1Mo + c], y1n1 = sR[e2][Y10o + c], y1n2 = sR[e2][Y1Po + c];
        float y2n0 = sR[e2][Y2M2o + c], y2n1 = sR[e2][Y2M1o + c], y2n2 = sR[e2][Y20o + c];
        float y2n3 = sR[e2][Y2P1o + c], y2n4 = sR[e2][Y2P2o + c];
        sR[e2][SCALo + c] = scv;
#pragma unroll
        for (int m = 0; m < 3; ++m) {
            float yw = sD1[e2][m]*y1n0 + sD1[e2][3+m]*y1n1 + sD1[e2][6+m]*y1n2;
            sR[e2][M1Go + 3*c + m] = yw * gg1;
        }
#pragma unroll
        for (int m = 0; m < 5; ++m) {
            float yw = sD2[e2][m]*y2n0 + sD2[e2][5+m]*y2n1 + sD2[e2][10+m]*y2n2
                     + sD2[e2][15+m]*y2n3 + sD2[e2][20+m]*y2n4;
            sR[e2][M2Go + 5*c + m] = yw * gg2;
        }
    }
    __syncthreads();

    // ---------------- stage 2b: wp projections + env gate + scatter ----------------
    const int ctrO = sCtr[e2];
    float* ob = out + (size_t)ctrO * 288;
#pragma unroll
    for (int di = 0; di < 2; ++di) {
        const int d = g + 16*di;
        float acc0 = 0.f;
        for (int c = 0; c < 32; ++c) acc0 += wp0[d*32 + c] * sR[e2][SCALo + c];
        float m0v = (acc0 * SCF + bp0[d]) * sR[e2][WENVo + d];
        atomicAdd(ob + d, COEFF * m0v);

        float b1[3] = {};
        for (int c = 0; c < 32; ++c) {
            float w = wp1[d*32 + c];
            b1[0] += w * sR[e2][M1Go + 3*c];
            b1[1] += w * sR[e2][M1Go + 3*c + 1];
            b1[2] += w * sR[e2][M1Go + 3*c + 2];
        }
        float wv1 = sR[e2][WENVo + 32 + d];
#pragma unroll
        for (int m = 0; m < 3; ++m) atomicAdd(ob + 32 + 3*d + m, COEFF * (b1[m] * SCF * wv1));

        float b2[5] = {};
        for (int c = 0; c < 32; ++c) {
            float w = wp2[d*32 + c];
            b2[0] += w * sR[e2][M2Go + 5*c];
            b2[1] += w * sR[e2][M2Go + 5*c + 1];
            b2[2] += w * sR[e2][M2Go + 5*c + 2];
            b2[3] += w * sR[e2][M2Go + 5*c + 3];
            b2[4] += w * sR[e2][M2Go + 5*c + 4];
        }
        float wv2 = sR[e2][WENVo + 64 + d];
#pragma unroll
        for (int m = 0; m < 5; ++m) atomicAdd(ob + 128 + 5*d + m, COEFF * (b2[m] * SCF * wv2));
    }
}

extern "C" void kernel_launch(void* const* d_in, const int* in_sizes, int n_in,
                              void* d_out, int out_size, void* d_ws, size_t ws_size,
                              hipStream_t stream)
{
    const float* latents = (const float*)d_in[0];
    const float* nf      = (const float*)d_in[1];
    const float* efe     = (const float*)d_in[2];
    const float* evec    = (const float*)d_in[3];
    const int*   eidx    = (const int*)d_in[5];
    const int*   act     = (const int*)d_in[6];
    const float* g0n = (const float*)d_in[7];
    const float* b0n = (const float*)d_in[8];
    const float* g1n = (const float*)d_in[9];
    const float* g2n = (const float*)d_in[10];
    const float* g0e = (const float*)d_in[11];
    const float* b0e = (const float*)d_in[12];
    const float* g1e = (const float*)d_in[13];
    const float* g2e = (const float*)d_in[14];
    const float* w0s = (const float*)d_in[15];
    const float* w01 = (const float*)d_in[16];
    const float* w02 = (const float*)d_in[17];
    const float* wr11 = (const float*)d_in[18];
    const float* wi11 = (const float*)d_in[19];
    const float* wr12 = (const float*)d_in[20];
    const float* wi12 = (const float*)d_in[21];
    const float* wr22 = (const float*)d_in[22];
    const float* wi22 = (const float*)d_in[23];
    const float* wp0 = (const float*)d_in[24];
    const float* bp0 = (const float*)d_in[25];
    const float* wp1 = (const float*)d_in[26];
    const float* wp2 = (const float*)d_in[27];
    const float* wenv = (const float*)d_in[28];
    const float* benv = (const float*)d_in[29];
    float* out = (float*)d_out;
    float* nrm = (float*)d_ws;   // N*288 floats = 11.52 MB

    node_norm_k<<<(NN + 3) / 4, 256, 0, stream>>>(nf, g0n, b0n, g1n, g2n, nrm, out);
    edge_k<<<EE / NE, 256, 0, stream>>>(latents, efe, evec, eidx, act,
        g0e, b0e, g1e, g2e, w0s, w01, w02, wr11, wi11, wr12, wi12, wr22, wi22,
        wp0, bp0, wp1, wp2, wenv, benv, nrm, out);
}

// Round 2
// 1039.656 us; speedup vs baseline: 1.8258x; 1.8258x over previous
//
#include <hip/hip_runtime.h>
#include <math.h>

#define NN 10000
#define EE 100000
#define EPB 16          // edges per block
#define AST 1000        // sA row stride (ushorts), padded (2000B -> 2-way-ish banks)
#define YST 452         // sY row stride (floats)

// staged-input segment offsets within an sA row (ushort index)
#define SEG0 0          // in0 (288)
#define SEGP1 288       // xp1||xm1 part a: x1[:,:,2](96) + x2[:,:,3](96)
#define SEGM1 480       // x1[:,:,0](96) + x2[:,:,1](96)
#define SEGP2 672       // x2[:,:,4](96)
#define SEGM2 768       // x2[:,:,0](96)
#define SEGL 864        // latents (128)

// sY per-edge layout (floats)
#define Y0o   0
#define Y10o  96
#define Y20o  128
#define Y1Po  160
#define Y1Mo  192
#define Y2P1o 224
#define Y2M1o 256
#define Y2P2o 288
#define Y2M2o 320
#define WENVo 352

// packed-weight region offsets (ushort index within pack area)
#define PK1 0           // [10][9][64][8]   160x288
#define PK2 46080       // [8][12][64][8]   128x384
#define PK3 95232       // [4][6][64][8]    64x192
#define PK4 107520      // [6][4][64][8]    96x128
#define PKTOT 119808
#define NRM_FLOATS (NN*288)

#define SQ3F  1.7320508075688772f
#define S0F   0.05892556509887896f   // 1/sqrt(288)
#define S1F   0.07216878364870323f   // 1/sqrt(192)
#define S2F   0.10206207261596575f   // 1/sqrt(96)
#define SEF   0.08838834764831845f   // 1/sqrt(128)
#define SCF   0.17677669529663687f   // 1/sqrt(32)
#define COLDF 0.8944271909999159f    // 1/sqrt(1.25)
#define COEFF 0.1414213562373095f    // 0.5/sqrt(1.25)/sqrt(10)

typedef __attribute__((ext_vector_type(8))) short bf16x8;
typedef __attribute__((ext_vector_type(4))) float f32x4;

__device__ __forceinline__ ushort f2bf(float f) {
    union { float f; unsigned u; } v; v.f = f;
    unsigned r = v.u + 0x7fff + ((v.u >> 16) & 1);
    return (ushort)(r >> 16);
}
__device__ __forceinline__ float4 ld4(const float* p) { return *reinterpret_cast<const float4*>(p); }

// ---------------- weight pre-pack: MFMA B-frag order, bf16 ----------------
__global__ __launch_bounds__(256) void pack_k(
    const float* __restrict__ w0s, const float* __restrict__ w01, const float* __restrict__ w02,
    const float* __restrict__ wr11, const float* __restrict__ wi11,
    const float* __restrict__ wr12, const float* __restrict__ wi12,
    const float* __restrict__ wr22, const float* __restrict__ wi22,
    const float* __restrict__ wenv, ushort* __restrict__ pk)
{
    int i = blockIdx.x * 256 + threadIdx.x;
    if (i >= PKTOT) return;
    float val;
    if (i < PK2) {
        int idx = i - PK1;
        int tile = idx / 4608, rem = idx % 4608;
        int chunk = rem / 512, rem2 = rem % 512;
        int lane = rem2 / 8, j = rem2 % 8;
        int col = tile * 16 + (lane & 15);
        int k = chunk * 32 + (lane >> 4) * 8 + j;
        if (col < 96)       val = w0s[col * 288 + k];
        else if (col < 128) val = w01[(col - 96) * 288 + k];
        else                val = w02[(col - 128) * 288 + k];
    } else if (i < PK3) {
        int idx = i - PK2;
        int tile = idx / 6144, rem = idx % 6144;
        int chunk = rem / 512, rem2 = rem % 512;
        int lane = rem2 / 8, j = rem2 % 8;
        int col = tile * 16 + (lane & 15);
        int k = chunk * 32 + (lane >> 4) * 8 + j;
        int grp = col >> 5, c = col & 31;
        if (k < 192) {
            val = (grp == 0) ? wr11[c*192 + k] : (grp == 1) ? wi11[c*192 + k]
                : (grp == 2) ? wr12[c*192 + k] : wi12[c*192 + k];
        } else {
            int kk = k - 192;
            val = (grp == 0) ? -wi11[c*192 + kk] : (grp == 1) ? wr11[c*192 + kk]
                : (grp == 2) ? -wi12[c*192 + kk] : wr12[c*192 + kk];
        }
    } else if (i < PK4) {
        int idx = i - PK3;
        int tile = idx / 3072, rem = idx % 3072;
        int chunk = rem / 512, rem2 = rem % 512;
        int lane = rem2 / 8, j = rem2 % 8;
        int col = tile * 16 + (lane & 15);
        int k = chunk * 32 + (lane >> 4) * 8 + j;
        int grp = col >> 5, c = col & 31;
        if (k < 96) val = grp ? wi22[c*96 + k] : wr22[c*96 + k];
        else        val = grp ? wr22[c*96 + k - 96] : -wi22[c*96 + k - 96];
    } else {
        int idx = i - PK4;
        int tile = idx / 2048, rem = idx % 2048;
        int chunk = rem / 512, rem2 = rem % 512;
        int lane = rem2 / 8, j = rem2 % 8;
        int col = tile * 16 + (lane & 15);
        int k = chunk * 32 + (lane >> 4) * 8 + j;
        val = wenv[col * 128 + k];
    }
    pk[i] = f2bf(val);
}

// ---------------- node SLN ----------------
__global__ __launch_bounds__(256) void node_norm_k(
    const float* __restrict__ nf,
    const float* __restrict__ g0, const float* __restrict__ b0,
    const float* __restrict__ g1, const float* __restrict__ g2,
    float* __restrict__ nrm, float* __restrict__ out)
{
    int row = blockIdx.x * 4 + (threadIdx.x >> 6);
    if (row >= NN) return;
    int lane = threadIdx.x & 63;
    const float* r = nf + (size_t)row * 288;
    float v0 = r[lane];
    float v1 = r[lane + 64];
    float v2 = r[lane + 128];
    float v3 = r[lane + 192];
    float v4 = (lane < 32) ? r[lane + 256] : 0.f;
    float s0 = 0.f, s0q = 0.f, q1 = 0.f, q2 = 0.f;
    if (lane < 32) { s0 = v0; s0q = v0*v0; } else { q1 = v0*v0; }
    q1 += v1*v1;
    q2 += v2*v2 + v3*v3 + v4*v4;
#pragma unroll
    for (int m = 1; m < 64; m <<= 1) {
        s0  += __shfl_xor(s0, m);
        s0q += __shfl_xor(s0q, m);
        q1  += __shfl_xor(q1, m);
        q2  += __shfl_xor(q2, m);
    }
    float mu  = s0 * (1.f/32.f);
    float var = s0q * (1.f/32.f) - mu*mu;
    float rs0 = rsqrtf(var + 1e-8f);
    float rv  = 0.5f * (q1 * (1.f/96.f) + q2 * (1.f/160.f));
    float rs  = rsqrtf(rv + 1e-8f);
    float* nr = nrm + (size_t)row * 288;
    float* orow = out + (size_t)row * 288;
    {
        float res;
        if (lane < 32) res = (v0 - mu) * rs0 * g0[lane] + b0[lane];
        else { int c = (lane - 32) / 3; res = v0 * rs * g1[c]; }
        nr[lane] = res; orow[lane] = COLDF * v0;
    }
    { int k = lane + 64;  int c = (k - 32) / 3;  nr[k] = v1 * rs * g1[c]; orow[k] = COLDF * v1; }
    { int k = lane + 128; int c = (k - 128) / 5; nr[k] = v2 * rs * g2[c]; orow[k] = COLDF * v2; }
    { int k = lane + 192; int c = (k - 128) / 5; nr[k] = v3 * rs * g2[c]; orow[k] = COLDF * v3; }
    if (lane < 32) { int k = lane + 256; int c = (k - 128) / 5; nr[k] = v4 * rs * g2[c]; orow[k] = COLDF * v4; }
}

// ---------------- fused edge kernel ----------------
__global__ __launch_bounds__(256) void edge_k(
    const float* __restrict__ lat, const float* __restrict__ ef,
    const float* __restrict__ evec,
    const int* __restrict__ eidx, const int* __restrict__ act,
    const float* __restrict__ g0e, const float* __restrict__ b0e,
    const float* __restrict__ g1e, const float* __restrict__ g2e,
    const ushort* __restrict__ pk,
    const float* __restrict__ wp0, const float* __restrict__ bp0,
    const float* __restrict__ wp1, const float* __restrict__ wp2,
    const float* __restrict__ benv,
    const float* __restrict__ nrm, float* __restrict__ out)
{
    __shared__ __align__(16) ushort sA[EPB * AST];
    __shared__ __align__(16) float sY[EPB * YST];
    __shared__ float sD1[EPB][12];
    __shared__ float sD2[EPB][28];
    __shared__ int sCtr[EPB];

    const int tid = threadIdx.x;
    const int wv = tid >> 6, lane = tid & 63;

    // ---------------- prep: wave per edge, 4 iterations ----------------
    for (int it = 0; it < 4; ++it) {
        const int e = it * 4 + wv;
        const int ge = blockIdx.x * EPB + e;
        const int ae = act[ge];
        const int ctr = eidx[ae], nbr = eidx[EE + ae];
        if (lane == 0) sCtr[e] = ctr;
        ushort* row = sA + e * AST;

        // local frame D1 rows (u, n, v)
        float vx = evec[3*ae], vy = evec[3*ae+1], vz = evec[3*ae+2];
        float nnv = fmaxf(sqrtf(vx*vx + vy*vy + vz*vz), 1e-9f);
        float nx = vx/nnv, ny = vy/nnv, nz = vz/nnv;
        float ax, az;
        if (fabsf(nx) < 0.9f) { ax = 1.f; az = 0.f; } else { ax = 0.f; az = 1.f; }
        float adn = ax*nx + az*nz;
        float ux = ax - adn*nx, uy = -adn*ny, uz = az - adn*nz;
        float un = fmaxf(sqrtf(ux*ux + uy*uy + uz*uz), 1e-9f);
        ux /= un; uy /= un; uz /= un;
        float wx = uy*nz - uz*ny, wy = uz*nx - ux*nz, wz = ux*ny - uy*nx;

        // analytic l=2 Wigner of D1
        float d2[5][5];
        d2[0][0] = wz*ux + uz*wx;  d2[0][1] = wx*uy + ux*wy;  d2[0][2] = SQ3F*wy*uy;
        d2[0][3] = wy*uz + uy*wz;  d2[0][4] = wz*uz - wx*ux;
        d2[1][0] = uz*nx + nz*ux;  d2[1][1] = ux*ny + nx*uy;  d2[1][2] = SQ3F*uy*ny;
        d2[1][3] = uy*nz + ny*uz;  d2[1][4] = uz*nz - ux*nx;
        d2[2][0] = SQ3F*nz*nx;     d2[2][1] = SQ3F*nx*ny;     d2[2][2] = 1.5f*ny*ny - 0.5f;
        d2[2][3] = SQ3F*ny*nz;     d2[2][4] = 0.5f*SQ3F*(nz*nz - nx*nx);
        d2[3][0] = nz*wx + wz*nx;  d2[3][1] = nx*wy + wx*ny;  d2[3][2] = SQ3F*ny*wy;
        d2[3][3] = ny*wz + wy*nz;  d2[3][4] = nz*wz - nx*wx;
        d2[4][0] = wz*wx - uz*ux;  d2[4][1] = wx*wy - ux*uy;  d2[4][2] = 0.5f*SQ3F*(wy*wy - uy*uy);
        d2[4][3] = wy*wz - uy*uz;  d2[4][4] = 0.5f*(wz*wz - uz*uz - wx*wx + ux*ux);

        // edge-feature SLN stats
        const float* efr = ef + (size_t)ae * 288;
        float ev0 = efr[lane];
        float ev1 = efr[lane + 64];
        float ev2 = efr[lane + 128];
        float ev3 = efr[lane + 192];
        float ev4 = (lane < 32) ? efr[lane + 256] : 0.f;
        float s0 = 0.f, s0q = 0.f, q1 = 0.f, q2 = 0.f;
        if (lane < 32) { s0 = ev0; s0q = ev0*ev0; } else { q1 = ev0*ev0; }
        q1 += ev1*ev1;
        q2 += ev2*ev2 + ev3*ev3 + ev4*ev4;
#pragma unroll
        for (int m = 1; m < 64; m <<= 1) {
            s0  += __shfl_xor(s0, m);
            s0q += __shfl_xor(s0q, m);
            q1  += __shfl_xor(q1, m);
            q2  += __shfl_xor(q2, m);
        }
        float mu  = s0 * (1.f/32.f);
        float rs0 = rsqrtf(s0q*(1.f/32.f) - mu*mu + 1e-8f);
        float rs  = rsqrtf(0.5f*(q1*(1.f/96.f) + q2*(1.f/160.f)) + 1e-8f);

        // scalar (l=0) part of in0
        if (lane < 32) {
            row[SEG0 + 32 + lane] = f2bf((ev0 - mu) * rs0 * g0e[lane] + b0e[lane]);
            row[SEG0 + lane]      = f2bf(nrm[(size_t)ctr*288 + lane]);
            row[SEG0 + 64 + lane] = f2bf(nrm[(size_t)nbr*288 + lane]);
        }
        // latents -> bf16
        {
            const float* lr = lat + (size_t)ae * 128;
            row[SEGL + lane]      = f2bf(lr[lane]);
            row[SEGL + 64 + lane] = f2bf(lr[lane + 64]);
        }

        // rotate l=1/l=2 channels into staged layout (bf16)
#pragma unroll
        for (int half = 0; half < 2; ++half) {
            const int cc = lane + 64*half;
            if (cc < 96) {
                float x1v[3], x2v[5];
                if (cc < 32) {
                    const float* b = nrm + (size_t)ctr * 288;
                    const int c = cc;
                    x1v[0] = b[32+3*c]; x1v[1] = b[33+3*c]; x1v[2] = b[34+3*c];
                    x2v[0] = b[128+5*c]; x2v[1] = b[129+5*c]; x2v[2] = b[130+5*c];
                    x2v[3] = b[131+5*c]; x2v[4] = b[132+5*c];
                } else if (cc < 64) {
                    const int c = cc - 32;
                    const float sa = rs * g1e[c], sb = rs * g2e[c];
                    x1v[0] = efr[32+3*c]*sa; x1v[1] = efr[33+3*c]*sa; x1v[2] = efr[34+3*c]*sa;
                    x2v[0] = efr[128+5*c]*sb; x2v[1] = efr[129+5*c]*sb; x2v[2] = efr[130+5*c]*sb;
                    x2v[3] = efr[131+5*c]*sb; x2v[4] = efr[132+5*c]*sb;
                } else {
                    const float* b = nrm + (size_t)nbr * 288;
                    const int c = cc - 64;
                    x1v[0] = b[32+3*c]; x1v[1] = b[33+3*c]; x1v[2] = b[34+3*c];
                    x2v[0] = b[128+5*c]; x2v[1] = b[129+5*c]; x2v[2] = b[130+5*c];
                    x2v[3] = b[131+5*c]; x2v[4] = b[132+5*c];
                }
                float r0 = ux*x1v[0] + uy*x1v[1] + uz*x1v[2];
                float r1 = nx*x1v[0] + ny*x1v[1] + nz*x1v[2];
                float r2 = wx*x1v[0] + wy*x1v[1] + wz*x1v[2];
                float t[5];
#pragma unroll
                for (int m = 0; m < 5; ++m)
                    t[m] = d2[m][0]*x2v[0] + d2[m][1]*x2v[1] + d2[m][2]*x2v[2]
                         + d2[m][3]*x2v[3] + d2[m][4]*x2v[4];
                row[SEG0 + 96  + cc] = f2bf(r1);   // x1[:,:,1]
                row[SEG0 + 192 + cc] = f2bf(t[2]); // x2[:,:,2]
                row[SEGP1 + cc]      = f2bf(r2);   // x1[:,:,2]
                row[SEGP1 + 96 + cc] = f2bf(t[3]); // x2[:,:,3]
                row[SEGM1 + cc]      = f2bf(r0);   // x1[:,:,0]
                row[SEGM1 + 96 + cc] = f2bf(t[1]); // x2[:,:,1]
                row[SEGP2 + cc]      = f2bf(t[4]); // x2[:,:,4]
                row[SEGM2 + cc]      = f2bf(t[0]); // x2[:,:,0]
            }
        }
        if (lane == 0) {
            sD1[e][0] = ux; sD1[e][1] = uy; sD1[e][2] = uz;
            sD1[e][3] = nx; sD1[e][4] = ny; sD1[e][5] = nz;
            sD1[e][6] = wx; sD1[e][7] = wy; sD1[e][8] = wz;
#pragma unroll
            for (int n = 0; n < 5; ++n)
#pragma unroll
                for (int m = 0; m < 5; ++m) sD2[e][5*n + m] = d2[n][m];
        }
    }
    __syncthreads();

    // ---------------- MFMA GEMM phase: 28 tiles across 4 waves ----------------
    for (int t = wv; t < 28; t += 4) {
        int kbase, nch, yoff, pbase; float scale;
        if (t < 10)      { kbase = SEG0;  nch = 9;  yoff = t*16;          scale = S0F; pbase = PK1 + t*9*512; }
        else if (t < 18) { kbase = SEGP1; nch = 12; yoff = 160+(t-10)*16; scale = S1F; pbase = PK2 + (t-10)*12*512; }
        else if (t < 22) { kbase = SEGP2; nch = 6;  yoff = 288+(t-18)*16; scale = S2F; pbase = PK3 + (t-18)*6*512; }
        else             { kbase = SEGL;  nch = 4;  yoff = 352+(t-22)*16; scale = SEF; pbase = PK4 + (t-22)*4*512; }
        f32x4 acc = {0.f, 0.f, 0.f, 0.f};
        const ushort* pa = sA + (lane & 15) * AST + kbase + (lane >> 4) * 8;
        const ushort* pb = pk + pbase + lane * 8;
        for (int ch = 0; ch < nch; ++ch) {
            bf16x8 a = *reinterpret_cast<const bf16x8*>(pa + ch * 32);
            bf16x8 b = *reinterpret_cast<const bf16x8*>(pb + ch * 512);
            acc = __builtin_amdgcn_mfma_f32_16x16x32_bf16(a, b, acc, 0, 0, 0);
        }
        const int col = yoff + (lane & 15);
        const int r0 = (lane >> 4) * 4;
        float bv = (t >= 22) ? benv[col - 352] : 0.f;
#pragma unroll
        for (int j = 0; j < 4; ++j)
            sY[(r0 + j) * YST + col] = acc[j] * scale + bv;
    }
    __syncthreads();

    // ---------------- stage 2a: gates + rotate-back ----------------
    const int e2 = tid & 15, g = tid >> 4;
    const float* yrow = sY + e2 * YST;
    float* sF = reinterpret_cast<float*>(sA) + e2 * 500;   // reuse sA: SCAL[0..31], M1G[32..127], M2G[128..287]
#pragma unroll
    for (int ci = 0; ci < 2; ++ci) {
        const int c = g + 16*ci;
        float y0v = yrow[Y0o + c];
        float scv = y0v / (1.f + expf(-y0v));
        float gg1 = 1.f / (1.f + expf(-yrow[Y0o + 32 + c]));
        float gg2 = 1.f / (1.f + expf(-yrow[Y0o + 64 + c]));
        float y1n0 = yrow[Y1Mo + c], y1n1 = yrow[Y10o + c], y1n2 = yrow[Y1Po + c];
        float y2n0 = yrow[Y2M2o + c], y2n1 = yrow[Y2M1o + c], y2n2 = yrow[Y20o + c];
        float y2n3 = yrow[Y2P1o + c], y2n4 = yrow[Y2P2o + c];
        sF[c] = scv;
#pragma unroll
        for (int m = 0; m < 3; ++m) {
            float yw = sD1[e2][m]*y1n0 + sD1[e2][3+m]*y1n1 + sD1[e2][6+m]*y1n2;
            sF[32 + 3*c + m] = yw * gg1;
        }
#pragma unroll
        for (int m = 0; m < 5; ++m) {
            float yw = sD2[e2][m]*y2n0 + sD2[e2][5+m]*y2n1 + sD2[e2][10+m]*y2n2
                     + sD2[e2][15+m]*y2n3 + sD2[e2][20+m]*y2n4;
            sF[128 + 5*c + m] = yw * gg2;
        }
    }
    __syncthreads();

    // ---------------- stage 2b: wp projections + env gate + scatter ----------------
    const int ctrO = sCtr[e2];
    float* ob = out + (size_t)ctrO * 288;
#pragma unroll
    for (int di = 0; di < 2; ++di) {
        const int d = g + 16*di;
        float acc0 = 0.f;
        for (int c = 0; c < 32; ++c) acc0 += wp0[d*32 + c] * sF[c];
        float m0v = (acc0 * SCF + bp0[d]) * yrow[WENVo + d];
        atomicAdd(ob + d, COEFF * m0v);

        float b1[3] = {};
        for (int c = 0; c < 32; ++c) {
            float w = wp1[d*32 + c];
            b1[0] += w * sF[32 + 3*c];
            b1[1] += w * sF[32 + 3*c + 1];
            b1[2] += w * sF[32 + 3*c + 2];
        }
        float wv1 = yrow[WENVo + 32 + d];
#pragma unroll
        for (int m = 0; m < 3; ++m) atomicAdd(ob + 32 + 3*d + m, COEFF * (b1[m] * SCF * wv1));

        float b2[5] = {};
        for (int c = 0; c < 32; ++c) {
            float w = wp2[d*32 + c];
            b2[0] += w * sF[128 + 5*c];
            b2[1] += w * sF[128 + 5*c + 1];
            b2[2] += w * sF[128 + 5*c + 2];
            b2[3] += w * sF[128 + 5*c + 3];
            b2[4] += w * sF[128 + 5*c + 4];
        }
        float wv2 = yrow[WENVo + 64 + d];
#pragma unroll
        for (int m = 0; m < 5; ++m) atomicAdd(ob + 128 + 5*d + m, COEFF * (b2[m] * SCF * wv2));
    }
}

extern "C" void kernel_launch(void* const* d_in, const int* in_sizes, int n_in,
                              void* d_out, int out_size, void* d_ws, size_t ws_size,
                              hipStream_t stream)
{
    const float* latents = (const float*)d_in[0];
    const float* nf      = (const float*)d_in[1];
    const float* efe     = (const float*)d_in[2];
    const float* evec    = (const float*)d_in[3];
    const int*   eidx    = (const int*)d_in[5];
    const int*   act     = (const int*)d_in[6];
    const float* g0n = (const float*)d_in[7];
    const float* b0n = (const float*)d_in[8];
    const float* g1n = (const float*)d_in[9];
    const float* g2n = (const float*)d_in[10];
    const float* g0e = (const float*)d_in[11];
    const float* b0e = (const float*)d_in[12];
    const float* g1e = (const float*)d_in[13];
    const float* g2e = (const float*)d_in[14];
    const float* w0s = (const float*)d_in[15];
    const float* w01 = (const float*)d_in[16];
    const float* w02 = (const float*)d_in[17];
    const float* wr11 = (const float*)d_in[18];
    const float* wi11 = (const float*)d_in[19];
    const float* wr12 = (const float*)d_in[20];
    const float* wi12 = (const float*)d_in[21];
    const float* wr22 = (const float*)d_in[22];
    const float* wi22 = (const float*)d_in[23];
    const float* wp0 = (const float*)d_in[24];
    const float* bp0 = (const float*)d_in[25];
    const float* wp1 = (const float*)d_in[26];
    const float* wp2 = (const float*)d_in[27];
    const float* wenv = (const float*)d_in[28];
    const float* benv = (const float*)d_in[29];
    float* out = (float*)d_out;
    float* nrm = (float*)d_ws;                         // N*288 f32 = 11.52 MB
    ushort* pkw = (ushort*)((char*)d_ws + (size_t)NRM_FLOATS * 4);  // 240 KB packed bf16 weights

    pack_k<<<(PKTOT + 255) / 256, 256, 0, stream>>>(w0s, w01, w02, wr11, wi11, wr12, wi12,
                                                    wr22, wi22, wenv, pkw);
    node_norm_k<<<(NN + 3) / 4, 256, 0, stream>>>(nf, g0n, b0n, g1n, g2n, nrm, out);
    edge_k<<<EE / EPB, 256, 0, stream>>>(latents, efe, evec, eidx, act,
        g0e, b0e, g1e, g2e, pkw, wp0, bp0, wp1, wp2, benv, nrm, out);
}

// Round 3
// 724.530 us; speedup vs baseline: 2.6200x; 1.4349x over previous
//
#include <hip/hip_runtime.h>
#include <math.h>

#define NN 10000
#define EE 100000
#define EPB 16          // edges per block
#define AST 1000        // sA row stride (ushorts) -> 2000B rows, 2-way bank aliasing (free)
#define YST 452         // sY row stride (floats)

// staged-input segment offsets within an sA row (ushort index)
#define SEG0 0          // in0 (288)
#define SEGP1 288       // x1[:,:,2](96) + x2[:,:,3](96)
#define SEGM1 480       // x1[:,:,0](96) + x2[:,:,1](96)
#define SEGP2 672       // x2[:,:,4](96)
#define SEGM2 768       // x2[:,:,0](96)
#define SEGL 864        // latents (128)

// sY per-edge layout (floats)
#define Y0o   0
#define Y10o  96
#define Y20o  128
#define Y1Po  160
#define Y1Mo  192
#define Y2P1o 224
#define Y2M1o 256
#define Y2P2o 288
#define Y2M2o 320
#define WENVo 352

// packed-weight region offsets (ushort index)
#define PK1 0           // [10][9][64][8]   160x288
#define PK2 46080       // [8][12][64][8]   128x384
#define PK3 95232       // [4][6][64][8]    64x192
#define PK4 107520      // [6][4][64][8]    96x128
#define PKTOT 119808
#define NRM_FLOATS (NN*288)

#define SQ3F  1.7320508075688772f
#define S0F   0.05892556509887896f
#define S1F   0.07216878364870323f
#define S2F   0.10206207261596575f
#define SEF   0.08838834764831845f
#define SCF   0.17677669529663687f
#define COLDF 0.8944271909999159f
#define COEFF 0.1414213562373095f

typedef __attribute__((ext_vector_type(8))) short bf16x8;
typedef __attribute__((ext_vector_type(4))) float f32x4;

__device__ __forceinline__ ushort f2bf(float f) {
    union { float f; unsigned u; } v; v.f = f;
    unsigned r = v.u + 0x7fff + ((v.u >> 16) & 1);
    return (ushort)(r >> 16);
}

// ---------------- weight pre-pack: MFMA B-frag order, bf16 ----------------
__global__ __launch_bounds__(256) void pack_k(
    const float* __restrict__ w0s, const float* __restrict__ w01, const float* __restrict__ w02,
    const float* __restrict__ wr11, const float* __restrict__ wi11,
    const float* __restrict__ wr12, const float* __restrict__ wi12,
    const float* __restrict__ wr22, const float* __restrict__ wi22,
    const float* __restrict__ wenv, ushort* __restrict__ pk)
{
    int i = blockIdx.x * 256 + threadIdx.x;
    if (i >= PKTOT) return;
    float val;
    if (i < PK2) {
        int idx = i - PK1;
        int tile = idx / 4608, rem = idx % 4608;
        int chunk = rem / 512, rem2 = rem % 512;
        int lane = rem2 / 8, j = rem2 % 8;
        int col = tile * 16 + (lane & 15);
        int k = chunk * 32 + (lane >> 4) * 8 + j;
        if (col < 96)       val = w0s[col * 288 + k];
        else if (col < 128) val = w01[(col - 96) * 288 + k];
        else                val = w02[(col - 128) * 288 + k];
    } else if (i < PK3) {
        int idx = i - PK2;
        int tile = idx / 6144, rem = idx % 6144;
        int chunk = rem / 512, rem2 = rem % 512;
        int lane = rem2 / 8, j = rem2 % 8;
        int col = tile * 16 + (lane & 15);
        int k = chunk * 32 + (lane >> 4) * 8 + j;
        int grp = col >> 5, c = col & 31;
        if (k < 192) {
            val = (grp == 0) ? wr11[c*192 + k] : (grp == 1) ? wi11[c*192 + k]
                : (grp == 2) ? wr12[c*192 + k] : wi12[c*192 + k];
        } else {
            int kk = k - 192;
            val = (grp == 0) ? -wi11[c*192 + kk] : (grp == 1) ? wr11[c*192 + kk]
                : (grp == 2) ? -wi12[c*192 + kk] : wr12[c*192 + kk];
        }
    } else if (i < PK4) {
        int idx = i - PK3;
        int tile = idx / 3072, rem = idx % 3072;
        int chunk = rem / 512, rem2 = rem % 512;
        int lane = rem2 / 8, j = rem2 % 8;
        int col = tile * 16 + (lane & 15);
        int k = chunk * 32 + (lane >> 4) * 8 + j;
        int grp = col >> 5, c = col & 31;
        if (k < 96) val = grp ? wi22[c*96 + k] : wr22[c*96 + k];
        else        val = grp ? wr22[c*96 + k - 96] : -wi22[c*96 + k - 96];
    } else {
        int idx = i - PK4;
        int tile = idx / 2048, rem = idx % 2048;
        int chunk = rem / 512, rem2 = rem % 512;
        int lane = rem2 / 8, j = rem2 % 8;
        int col = tile * 16 + (lane & 15);
        int k = chunk * 32 + (lane >> 4) * 8 + j;
        val = wenv[col * 128 + k];
    }
    pk[i] = f2bf(val);
}

// ---------------- node SLN ----------------
__global__ __launch_bounds__(256) void node_norm_k(
    const float* __restrict__ nf,
    const float* __restrict__ g0, const float* __restrict__ b0,
    const float* __restrict__ g1, const float* __restrict__ g2,
    float* __restrict__ nrm, float* __restrict__ out)
{
    int row = blockIdx.x * 4 + (threadIdx.x >> 6);
    if (row >= NN) return;
    int lane = threadIdx.x & 63;
    const float* r = nf + (size_t)row * 288;
    float v0 = r[lane];
    float v1 = r[lane + 64];
    float v2 = r[lane + 128];
    float v3 = r[lane + 192];
    float v4 = (lane < 32) ? r[lane + 256] : 0.f;
    float s0 = 0.f, s0q = 0.f, q1 = 0.f, q2 = 0.f;
    if (lane < 32) { s0 = v0; s0q = v0*v0; } else { q1 = v0*v0; }
    q1 += v1*v1;
    q2 += v2*v2 + v3*v3 + v4*v4;
#pragma unroll
    for (int m = 1; m < 64; m <<= 1) {
        s0  += __shfl_xor(s0, m);
        s0q += __shfl_xor(s0q, m);
        q1  += __shfl_xor(q1, m);
        q2  += __shfl_xor(q2, m);
    }
    float mu  = s0 * (1.f/32.f);
    float var = s0q * (1.f/32.f) - mu*mu;
    float rs0 = rsqrtf(var + 1e-8f);
    float rv  = 0.5f * (q1 * (1.f/96.f) + q2 * (1.f/160.f));
    float rs  = rsqrtf(rv + 1e-8f);
    float* nr = nrm + (size_t)row * 288;
    float* orow = out + (size_t)row * 288;
    {
        float res;
        if (lane < 32) res = (v0 - mu) * rs0 * g0[lane] + b0[lane];
        else { int c = (lane - 32) / 3; res = v0 * rs * g1[c]; }
        nr[lane] = res; orow[lane] = COLDF * v0;
    }
    { int k = lane + 64;  int c = (k - 32) / 3;  nr[k] = v1 * rs * g1[c]; orow[k] = COLDF * v1; }
    { int k = lane + 128; int c = (k - 128) / 5; nr[k] = v2 * rs * g2[c]; orow[k] = COLDF * v2; }
    { int k = lane + 192; int c = (k - 128) / 5; nr[k] = v3 * rs * g2[c]; orow[k] = COLDF * v3; }
    if (lane < 32) { int k = lane + 256; int c = (k - 128) / 5; nr[k] = v4 * rs * g2[c]; orow[k] = COLDF * v4; }
}

// ---------------- fused edge kernel: 512 threads / 16 edges ----------------
__global__ __launch_bounds__(512, 4) void edge_k(
    const float* __restrict__ lat, const float* __restrict__ ef,
    const float* __restrict__ evec,
    const int* __restrict__ eidx, const int* __restrict__ act,
    const float* __restrict__ g0e, const float* __restrict__ b0e,
    const float* __restrict__ g1e, const float* __restrict__ g2e,
    const ushort* __restrict__ pk,
    const float* __restrict__ wp0, const float* __restrict__ bp0,
    const float* __restrict__ wp1, const float* __restrict__ wp2,
    const float* __restrict__ benv,
    const float* __restrict__ nrm, float* __restrict__ out)
{
    __shared__ __align__(16) ushort sA[EPB * AST];
    __shared__ __align__(16) float sY[EPB * YST];
    __shared__ float sD1[EPB][12];
    __shared__ float sD2[EPB][28];
    __shared__ int sCtr[EPB];

    const int tid = threadIdx.x;
    const int wv = tid >> 6, lane = tid & 63;

    // ---------------- prep: wave per edge, 2 iterations ----------------
    for (int it = 0; it < 2; ++it) {
        const int e = it * 8 + wv;
        const int ge = blockIdx.x * EPB + e;
        const int ae = act[ge];
        const int ctr = eidx[ae], nbr = eidx[EE + ae];
        if (lane == 0) sCtr[e] = ctr;
        ushort* row = sA + e * AST;
        const float* efr = ef + (size_t)ae * 288;

        // --- edge SLN stats first (frees ev regs before frame/d2) ---
        float ev0 = efr[lane];
        float ev1 = efr[lane + 64];
        float ev2 = efr[lane + 128];
        float ev3 = efr[lane + 192];
        float ev4 = (lane < 32) ? efr[lane + 256] : 0.f;
        float s0 = 0.f, s0q = 0.f, q1 = 0.f, q2 = 0.f;
        if (lane < 32) { s0 = ev0; s0q = ev0*ev0; } else { q1 = ev0*ev0; }
        q1 += ev1*ev1;
        q2 += ev2*ev2 + ev3*ev3 + ev4*ev4;
#pragma unroll
        for (int m = 1; m < 64; m <<= 1) {
            s0  += __shfl_xor(s0, m);
            s0q += __shfl_xor(s0q, m);
            q1  += __shfl_xor(q1, m);
            q2  += __shfl_xor(q2, m);
        }
        float mu  = s0 * (1.f/32.f);
        float rs0 = rsqrtf(s0q*(1.f/32.f) - mu*mu + 1e-8f);
        float rs  = rsqrtf(0.5f*(q1*(1.f/96.f) + q2*(1.f/160.f)) + 1e-8f);

        // scalar (l=0) part of in0 + latents
        if (lane < 32) {
            row[SEG0 + 32 + lane] = f2bf((ev0 - mu) * rs0 * g0e[lane] + b0e[lane]);
            row[SEG0 + lane]      = f2bf(nrm[(size_t)ctr*288 + lane]);
            row[SEG0 + 64 + lane] = f2bf(nrm[(size_t)nbr*288 + lane]);
        }
        {
            const float* lr = lat + (size_t)ae * 128;
            row[SEGL + lane]      = f2bf(lr[lane]);
            row[SEGL + 64 + lane] = f2bf(lr[lane + 64]);
        }

        // --- local frame D1 rows (u, n, v) + analytic l=2 Wigner ---
        float vx = evec[3*ae], vy = evec[3*ae+1], vz = evec[3*ae+2];
        float nnv = fmaxf(sqrtf(vx*vx + vy*vy + vz*vz), 1e-9f);
        float nx = vx/nnv, ny = vy/nnv, nz = vz/nnv;
        float ax, az;
        if (fabsf(nx) < 0.9f) { ax = 1.f; az = 0.f; } else { ax = 0.f; az = 1.f; }
        float adn = ax*nx + az*nz;
        float ux = ax - adn*nx, uy = -adn*ny, uz = az - adn*nz;
        float un = fmaxf(sqrtf(ux*ux + uy*uy + uz*uz), 1e-9f);
        ux /= un; uy /= un; uz /= un;
        float wx = uy*nz - uz*ny, wy = uz*nx - ux*nz, wz = ux*ny - uy*nx;

        float d2[5][5];
        d2[0][0] = wz*ux + uz*wx;  d2[0][1] = wx*uy + ux*wy;  d2[0][2] = SQ3F*wy*uy;
        d2[0][3] = wy*uz + uy*wz;  d2[0][4] = wz*uz - wx*ux;
        d2[1][0] = uz*nx + nz*ux;  d2[1][1] = ux*ny + nx*uy;  d2[1][2] = SQ3F*uy*ny;
        d2[1][3] = uy*nz + ny*uz;  d2[1][4] = uz*nz - ux*nx;
        d2[2][0] = SQ3F*nz*nx;     d2[2][1] = SQ3F*nx*ny;     d2[2][2] = 1.5f*ny*ny - 0.5f;
        d2[2][3] = SQ3F*ny*nz;     d2[2][4] = 0.5f*SQ3F*(nz*nz - nx*nx);
        d2[3][0] = nz*wx + wz*nx;  d2[3][1] = nx*wy + wx*ny;  d2[3][2] = SQ3F*ny*wy;
        d2[3][3] = ny*wz + wy*nz;  d2[3][4] = nz*wz - nx*wx;
        d2[4][0] = wz*wx - uz*ux;  d2[4][1] = wx*wy - ux*uy;  d2[4][2] = 0.5f*SQ3F*(wy*wy - uy*uy);
        d2[4][3] = wy*wz - uy*uz;  d2[4][4] = 0.5f*(wz*wz - uz*uz - wx*wx + ux*ux);

        if (lane == 0) {
            sD1[e][0] = ux; sD1[e][1] = uy; sD1[e][2] = uz;
            sD1[e][3] = nx; sD1[e][4] = ny; sD1[e][5] = nz;
            sD1[e][6] = wx; sD1[e][7] = wy; sD1[e][8] = wz;
#pragma unroll
            for (int n = 0; n < 5; ++n)
#pragma unroll
                for (int m = 0; m < 5; ++m) sD2[e][5*n + m] = d2[n][m];
        }

        // rotate l=1/l=2 channels into staged layout (bf16)
#pragma unroll
        for (int half = 0; half < 2; ++half) {
            const int cc = lane + 64*half;
            if (cc < 96) {
                float x1v[3], x2v[5];
                if (cc < 32) {
                    const float* b = nrm + (size_t)ctr * 288;
                    const int c = cc;
                    x1v[0] = b[32+3*c]; x1v[1] = b[33+3*c]; x1v[2] = b[34+3*c];
                    x2v[0] = b[128+5*c]; x2v[1] = b[129+5*c]; x2v[2] = b[130+5*c];
                    x2v[3] = b[131+5*c]; x2v[4] = b[132+5*c];
                } else if (cc < 64) {
                    const int c = cc - 32;
                    const float sa = rs * g1e[c], sb = rs * g2e[c];
                    x1v[0] = efr[32+3*c]*sa; x1v[1] = efr[33+3*c]*sa; x1v[2] = efr[34+3*c]*sa;
                    x2v[0] = efr[128+5*c]*sb; x2v[1] = efr[129+5*c]*sb; x2v[2] = efr[130+5*c]*sb;
                    x2v[3] = efr[131+5*c]*sb; x2v[4] = efr[132+5*c]*sb;
                } else {
                    const float* b = nrm + (size_t)nbr * 288;
                    const int c = cc - 64;
                    x1v[0] = b[32+3*c]; x1v[1] = b[33+3*c]; x1v[2] = b[34+3*c];
                    x2v[0] = b[128+5*c]; x2v[1] = b[129+5*c]; x2v[2] = b[130+5*c];
                    x2v[3] = b[131+5*c]; x2v[4] = b[132+5*c];
                }
                float r0 = ux*x1v[0] + uy*x1v[1] + uz*x1v[2];
                float r1 = nx*x1v[0] + ny*x1v[1] + nz*x1v[2];
                float r2 = wx*x1v[0] + wy*x1v[1] + wz*x1v[2];
                float t[5];
#pragma unroll
                for (int m = 0; m < 5; ++m)
                    t[m] = d2[m][0]*x2v[0] + d2[m][1]*x2v[1] + d2[m][2]*x2v[2]
                         + d2[m][3]*x2v[3] + d2[m][4]*x2v[4];
                row[SEG0 + 96  + cc] = f2bf(r1);
                row[SEG0 + 192 + cc] = f2bf(t[2]);
                row[SEGP1 + cc]      = f2bf(r2);
                row[SEGP1 + 96 + cc] = f2bf(t[3]);
                row[SEGM1 + cc]      = f2bf(r0);
                row[SEGM1 + 96 + cc] = f2bf(t[1]);
                row[SEGP2 + cc]      = f2bf(t[4]);
                row[SEGM2 + cc]      = f2bf(t[0]);
            }
        }
    }
    __syncthreads();

    // ---------------- MFMA GEMM phase: 28 tiles across 8 waves ----------------
    for (int t = wv; t < 28; t += 8) {
        int kbase, nch, yoff, pbase; float scale;
        if (t < 10)      { kbase = SEG0;  nch = 9;  yoff = t*16;          scale = S0F; pbase = PK1 + t*9*512; }
        else if (t < 18) { kbase = SEGP1; nch = 12; yoff = 160+(t-10)*16; scale = S1F; pbase = PK2 + (t-10)*12*512; }
        else if (t < 22) { kbase = SEGP2; nch = 6;  yoff = 288+(t-18)*16; scale = S2F; pbase = PK3 + (t-18)*6*512; }
        else             { kbase = SEGL;  nch = 4;  yoff = 352+(t-22)*16; scale = SEF; pbase = PK4 + (t-22)*4*512; }
        f32x4 acc = {0.f, 0.f, 0.f, 0.f};
        const ushort* pa = sA + (lane & 15) * AST + kbase + (lane >> 4) * 8;
        const ushort* pb = pk + pbase + lane * 8;
        for (int ch = 0; ch < nch; ++ch) {
            bf16x8 a = *reinterpret_cast<const bf16x8*>(pa + ch * 32);
            bf16x8 b = *reinterpret_cast<const bf16x8*>(pb + ch * 512);
            acc = __builtin_amdgcn_mfma_f32_16x16x32_bf16(a, b, acc, 0, 0, 0);
        }
        const int col = yoff + (lane & 15);
        const int r0 = (lane >> 4) * 4;
        float bv = (t >= 22) ? benv[col - 352] : 0.f;
#pragma unroll
        for (int j = 0; j < 4; ++j)
            sY[(r0 + j) * YST + col] = acc[j] * scale + bv;
    }
    __syncthreads();

    // ---------------- stage 2a: gates + rotate-back (thread = edge x channel) ----------------
    const int e2 = tid & 15, c = tid >> 4;   // c in 0..31
    const float* yrow = sY + e2 * YST;
    float* sF = reinterpret_cast<float*>(sA) + e2 * 500;  // reuse sA
    {
        float y0v = yrow[Y0o + c];
        float scv = y0v / (1.f + expf(-y0v));
        float gg1 = 1.f / (1.f + expf(-yrow[Y0o + 32 + c]));
        float gg2 = 1.f / (1.f + expf(-yrow[Y0o + 64 + c]));
        float y1n0 = yrow[Y1Mo + c], y1n1 = yrow[Y10o + c], y1n2 = yrow[Y1Po + c];
        float y2n0 = yrow[Y2M2o + c], y2n1 = yrow[Y2M1o + c], y2n2 = yrow[Y20o + c];
        float y2n3 = yrow[Y2P1o + c], y2n4 = yrow[Y2P2o + c];
        sF[c] = scv;
#pragma unroll
        for (int m = 0; m < 3; ++m) {
            float yw = sD1[e2][m]*y1n0 + sD1[e2][3+m]*y1n1 + sD1[e2][6+m]*y1n2;
            sF[32 + 3*c + m] = yw * gg1;
        }
#pragma unroll
        for (int m = 0; m < 5; ++m) {
            float yw = sD2[e2][m]*y2n0 + sD2[e2][5+m]*y2n1 + sD2[e2][10+m]*y2n2
                     + sD2[e2][15+m]*y2n3 + sD2[e2][20+m]*y2n4;
            sF[128 + 5*c + m] = yw * gg2;
        }
    }
    __syncthreads();

    // ---------------- stage 2b: wp projections + env gate + scatter ----------------
    const int d = c;   // 0..31
    float* ob = out + (size_t)sCtr[e2] * 288;
    {
        float acc0 = 0.f;
        for (int cc = 0; cc < 32; ++cc) acc0 += wp0[d*32 + cc] * sF[cc];
        float m0v = (acc0 * SCF + bp0[d]) * yrow[WENVo + d];
        atomicAdd(ob + d, COEFF * m0v);

        float b1[3] = {};
        for (int cc = 0; cc < 32; ++cc) {
            float w = wp1[d*32 + cc];
            b1[0] += w * sF[32 + 3*cc];
            b1[1] += w * sF[32 + 3*cc + 1];
            b1[2] += w * sF[32 + 3*cc + 2];
        }
        float wv1 = yrow[WENVo + 32 + d];
#pragma unroll
        for (int m = 0; m < 3; ++m) atomicAdd(ob + 32 + 3*d + m, COEFF * (b1[m] * SCF * wv1));

        float b2[5] = {};
        for (int cc = 0; cc < 32; ++cc) {
            float w = wp2[d*32 + cc];
            b2[0] += w * sF[128 + 5*cc];
            b2[1] += w * sF[128 + 5*cc + 1];
            b2[2] += w * sF[128 + 5*cc + 2];
            b2[3] += w * sF[128 + 5*cc + 3];
            b2[4] += w * sF[128 + 5*cc + 4];
        }
        float wv2 = yrow[WENVo + 64 + d];
#pragma unroll
        for (int m = 0; m < 5; ++m) atomicAdd(ob + 128 + 5*d + m, COEFF * (b2[m] * SCF * wv2));
    }
}

extern "C" void kernel_launch(void* const* d_in, const int* in_sizes, int n_in,
                              void* d_out, int out_size, void* d_ws, size_t ws_size,
                              hipStream_t stream)
{
    const float* latents = (const float*)d_in[0];
    const float* nf      = (const float*)d_in[1];
    const float* efe     = (const float*)d_in[2];
    const float* evec    = (const float*)d_in[3];
    const int*   eidx    = (const int*)d_in[5];
    const int*   act     = (const int*)d_in[6];
    const float* g0n = (const float*)d_in[7];
    const float* b0n = (const float*)d_in[8];
    const float* g1n = (const float*)d_in[9];
    const float* g2n = (const float*)d_in[10];
    const float* g0e = (const float*)d_in[11];
    const float* b0e = (const float*)d_in[12];
    const float* g1e = (const float*)d_in[13];
    const float* g2e = (const float*)d_in[14];
    const float* w0s = (const float*)d_in[15];
    const float* w01 = (const float*)d_in[16];
    const float* w02 = (const float*)d_in[17];
    const float* wr11 = (const float*)d_in[18];
    const float* wi11 = (const float*)d_in[19];
    const float* wr12 = (const float*)d_in[20];
    const float* wi12 = (const float*)d_in[21];
    const float* wr22 = (const float*)d_in[22];
    const float* wi22 = (const float*)d_in[23];
    const float* wp0 = (const float*)d_in[24];
    const float* bp0 = (const float*)d_in[25];
    const float* wp1 = (const float*)d_in[26];
    const float* wp2 = (const float*)d_in[27];
    const float* wenv = (const float*)d_in[28];
    const float* benv = (const float*)d_in[29];
    float* out = (float*)d_out;
    float* nrm = (float*)d_ws;                         // N*288 f32 = 11.52 MB
    ushort* pkw = (ushort*)((char*)d_ws + (size_t)NRM_FLOATS * 4);  // 240 KB packed bf16 weights

    pack_k<<<(PKTOT + 255) / 256, 256, 0, stream>>>(w0s, w01, w02, wr11, wi11, wr12, wi12,
                                                    wr22, wi22, wenv, pkw);
    node_norm_k<<<(NN + 3) / 4, 256, 0, stream>>>(nf, g0n, b0n, g1n, g2n, nrm, out);
    edge_k<<<EE / EPB, 512, 0, stream>>>(latents, efe, evec, eidx, act,
        g0e, b0e, g1e, g2e, pkw, wp0, bp0, wp1, wp2, benv, nrm, out);
}

// Round 4
// 576.046 us; speedup vs baseline: 3.2953x; 1.2578x over previous
//
#include <hip/hip_runtime.h>
#include <math.h>

#define NN 10000
#define EE 100000
#define EPB 8           // edges per block
#define AST 1000        // sA row stride (ushorts)
#define YST 452         // sY row stride (floats)

// staged-input segment offsets within an sA row (ushort index)
#define SEG0 0          // in0 (288)
#define SEGP1 288       // x1[:,:,2](96) + x2[:,:,3](96)
#define SEGM1 480       // x1[:,:,0](96) + x2[:,:,1](96)
#define SEGP2 672       // x2[:,:,4](96)
#define SEGM2 768       // x2[:,:,0](96)
#define SEGL 864        // latents (128)

// sY per-edge layout (floats)
#define Y0o   0
#define Y10o  96
#define Y20o  128
#define Y1Po  160
#define Y1Mo  192
#define Y2P1o 224
#define Y2M1o 256
#define Y2P2o 288
#define Y2M2o 320
#define WENVo 352

// packed-weight region offsets (ushort index)
#define PK1 0           // [10][9][64][8]   160x288
#define PK2 46080       // [8][12][64][8]   128x384
#define PK3 95232       // [4][6][64][8]    64x192
#define PK4 107520      // [6][4][64][8]    96x128
#define PKTOT 119808
#define NRM_FLOATS (NN*288)

#define SQ3F  1.7320508075688772f
#define S0F   0.05892556509887896f
#define S1F   0.07216878364870323f
#define S2F   0.10206207261596575f
#define SEF   0.08838834764831845f
#define SCF   0.17677669529663687f
#define COLDF 0.8944271909999159f
#define COEFF 0.1414213562373095f

typedef __attribute__((ext_vector_type(8))) short bf16x8;
typedef __attribute__((ext_vector_type(4))) float f32x4;

__device__ __forceinline__ ushort f2bf(float f) {
    union { float f; unsigned u; } v; v.f = f;
    unsigned r = v.u + 0x7fff + ((v.u >> 16) & 1);
    return (ushort)(r >> 16);
}

// planar layout: l0 [0..31], x1 planes 32+32*m+c (m<3), x2 planes 128+32*m+c (m<5)
__device__ __forceinline__ int planar(int k) {
    if (k < 32) return k;
    if (k < 128) { int c = (k - 32) / 3, m = (k - 32) % 3; return 32 + 32*m + c; }
    int c = (k - 128) / 5, m = (k - 128) % 5; return 128 + 32*m + c;
}

// ---------------- weight pre-pack: MFMA B-frag order, bf16 ----------------
__global__ __launch_bounds__(256) void pack_k(
    const float* __restrict__ w0s, const float* __restrict__ w01, const float* __restrict__ w02,
    const float* __restrict__ wr11, const float* __restrict__ wi11,
    const float* __restrict__ wr12, const float* __restrict__ wi12,
    const float* __restrict__ wr22, const float* __restrict__ wi22,
    const float* __restrict__ wenv, ushort* __restrict__ pk)
{
    int i = blockIdx.x * 256 + threadIdx.x;
    if (i >= PKTOT) return;
    float val;
    if (i < PK2) {
        int idx = i - PK1;
        int tile = idx / 4608, rem = idx % 4608;
        int chunk = rem / 512, rem2 = rem % 512;
        int lane = rem2 / 8, j = rem2 % 8;
        int col = tile * 16 + (lane & 15);
        int k = chunk * 32 + (lane >> 4) * 8 + j;
        if (col < 96)       val = w0s[col * 288 + k];
        else if (col < 128) val = w01[(col - 96) * 288 + k];
        else                val = w02[(col - 128) * 288 + k];
    } else if (i < PK3) {
        int idx = i - PK2;
        int tile = idx / 6144, rem = idx % 6144;
        int chunk = rem / 512, rem2 = rem % 512;
        int lane = rem2 / 8, j = rem2 % 8;
        int col = tile * 16 + (lane & 15);
        int k = chunk * 32 + (lane >> 4) * 8 + j;
        int grp = col >> 5, c = col & 31;
        if (k < 192) {
            val = (grp == 0) ? wr11[c*192 + k] : (grp == 1) ? wi11[c*192 + k]
                : (grp == 2) ? wr12[c*192 + k] : wi12[c*192 + k];
        } else {
            int kk = k - 192;
            val = (grp == 0) ? -wi11[c*192 + kk] : (grp == 1) ? wr11[c*192 + kk]
                : (grp == 2) ? -wi12[c*192 + kk] : wr12[c*192 + kk];
        }
    } else if (i < PK4) {
        int idx = i - PK3;
        int tile = idx / 3072, rem = idx % 3072;
        int chunk = rem / 512, rem2 = rem % 512;
        int lane = rem2 / 8, j = rem2 % 8;
        int col = tile * 16 + (lane & 15);
        int k = chunk * 32 + (lane >> 4) * 8 + j;
        int grp = col >> 5, c = col & 31;
        if (k < 96) val = grp ? wi22[c*96 + k] : wr22[c*96 + k];
        else        val = grp ? wr22[c*96 + k - 96] : -wi22[c*96 + k - 96];
    } else {
        int idx = i - PK4;
        int tile = idx / 2048, rem = idx % 2048;
        int chunk = rem / 512, rem2 = rem % 512;
        int lane = rem2 / 8, j = rem2 % 8;
        int col = tile * 16 + (lane & 15);
        int k = chunk * 32 + (lane >> 4) * 8 + j;
        val = wenv[col * 128 + k];
    }
    pk[i] = f2bf(val);
}

// ---------------- node SLN -> planar nrm ----------------
__global__ __launch_bounds__(256) void node_norm_k(
    const float* __restrict__ nf,
    const float* __restrict__ g0, const float* __restrict__ b0,
    const float* __restrict__ g1, const float* __restrict__ g2,
    float* __restrict__ nrm, float* __restrict__ out)
{
    int row = blockIdx.x * 4 + (threadIdx.x >> 6);
    if (row >= NN) return;
    int lane = threadIdx.x & 63;
    const float* r = nf + (size_t)row * 288;
    float v0 = r[lane];
    float v1 = r[lane + 64];
    float v2 = r[lane + 128];
    float v3 = r[lane + 192];
    float v4 = (lane < 32) ? r[lane + 256] : 0.f;
    float s0 = 0.f, s0q = 0.f, q1 = 0.f, q2 = 0.f;
    if (lane < 32) { s0 = v0; s0q = v0*v0; } else { q1 = v0*v0; }
    q1 += v1*v1;
    q2 += v2*v2 + v3*v3 + v4*v4;
#pragma unroll
    for (int m = 1; m < 64; m <<= 1) {
        s0  += __shfl_xor(s0, m);
        s0q += __shfl_xor(s0q, m);
        q1  += __shfl_xor(q1, m);
        q2  += __shfl_xor(q2, m);
    }
    float mu  = s0 * (1.f/32.f);
    float var = s0q * (1.f/32.f) - mu*mu;
    float rs0 = rsqrtf(var + 1e-8f);
    float rv  = 0.5f * (q1 * (1.f/96.f) + q2 * (1.f/160.f));
    float rs  = rsqrtf(rv + 1e-8f);
    float* nr = nrm + (size_t)row * 288;
    float* orow = out + (size_t)row * 288;
    {
        float res;
        if (lane < 32) res = (v0 - mu) * rs0 * g0[lane] + b0[lane];
        else { int c = (lane - 32) / 3; res = v0 * rs * g1[c]; }
        nr[planar(lane)] = res; orow[lane] = COLDF * v0;
    }
    { int k = lane + 64;  int c = (k - 32) / 3;  nr[planar(k)] = v1 * rs * g1[c]; orow[k] = COLDF * v1; }
    { int k = lane + 128; int c = (k - 128) / 5; nr[planar(k)] = v2 * rs * g2[c]; orow[k] = COLDF * v2; }
    { int k = lane + 192; int c = (k - 128) / 5; nr[planar(k)] = v3 * rs * g2[c]; orow[k] = COLDF * v3; }
    if (lane < 32) { int k = lane + 256; int c = (k - 128) / 5; nr[planar(k)] = v4 * rs * g2[c]; orow[k] = COLDF * v4; }
}

// ---------------- fused edge kernel: 256 threads / 8 edges ----------------
__global__ __launch_bounds__(256, 5) void edge_k(
    const float* __restrict__ lat, const float* __restrict__ ef,
    const float* __restrict__ evec,
    const int* __restrict__ eidx, const int* __restrict__ act,
    const float* __restrict__ g0e, const float* __restrict__ b0e,
    const float* __restrict__ g1e, const float* __restrict__ g2e,
    const ushort* __restrict__ pk,
    const float* __restrict__ wp0, const float* __restrict__ bp0,
    const float* __restrict__ wp1, const float* __restrict__ wp2,
    const float* __restrict__ benv,
    const float* __restrict__ nrm, float* __restrict__ out)
{
    __shared__ __align__(16) ushort sA[EPB * AST];
    __shared__ __align__(16) float sY[EPB * YST];
    __shared__ float sD1[EPB][12];
    __shared__ float sD2[EPB][28];
    __shared__ int sCtr[EPB];

    const int tid = threadIdx.x;
    const int wv = tid >> 6, lane = tid & 63;

    // ---------------- prep: wave per edge, 2 iterations ----------------
    for (int it = 0; it < 2; ++it) {
        const int e = it * 4 + wv;
        const int ge = blockIdx.x * EPB + e;
        const int ae = act[ge];
        const int ctr = eidx[ae], nbr = eidx[EE + ae];
        if (lane == 0) sCtr[e] = ctr;
        ushort* row = sA + e * AST;
        float* sE = sY + e * YST;      // f32 planar staging for this edge's features
        const float* efr = ef + (size_t)ae * 288;

        // --- edge SLN stats (coalesced loads) ---
        float ev0 = efr[lane];
        float ev1 = efr[lane + 64];
        float ev2 = efr[lane + 128];
        float ev3 = efr[lane + 192];
        float ev4 = (lane < 32) ? efr[lane + 256] : 0.f;
        float s0 = 0.f, s0q = 0.f, q1 = 0.f, q2 = 0.f;
        if (lane < 32) { s0 = ev0; s0q = ev0*ev0; } else { q1 = ev0*ev0; }
        q1 += ev1*ev1;
        q2 += ev2*ev2 + ev3*ev3 + ev4*ev4;
#pragma unroll
        for (int m = 1; m < 64; m <<= 1) {
            s0  += __shfl_xor(s0, m);
            s0q += __shfl_xor(s0q, m);
            q1  += __shfl_xor(q1, m);
            q2  += __shfl_xor(q2, m);
        }
        float mu  = s0 * (1.f/32.f);
        float rs0 = rsqrtf(s0q*(1.f/32.f) - mu*mu + 1e-8f);
        float rs  = rsqrtf(0.5f*(q1*(1.f/96.f) + q2*(1.f/160.f)) + 1e-8f);

        // --- stage scaled edge x1/x2 into planar f32 LDS ---
        if (lane >= 32) { int c = (lane-32)/3, m = (lane-32)%3; sE[32 + 32*m + c] = ev0 * rs * g1e[c]; }
        { int k = lane+64;  int c = (k-32)/3,  m = (k-32)%3;  sE[32 + 32*m + c]  = ev1 * rs * g1e[c]; }
        { int k = lane+128; int c = (k-128)/5, m = (k-128)%5; sE[128 + 32*m + c] = ev2 * rs * g2e[c]; }
        { int k = lane+192; int c = (k-128)/5, m = (k-128)%5; sE[128 + 32*m + c] = ev3 * rs * g2e[c]; }
        if (lane < 32) { int k = lane+256; int c = (k-128)/5, m = (k-128)%5; sE[128 + 32*m + c] = ev4 * rs * g2e[c]; }

        // scalar (l=0) part of in0 + latents
        if (lane < 32) {
            row[SEG0 + 32 + lane] = f2bf((ev0 - mu) * rs0 * g0e[lane] + b0e[lane]);
            row[SEG0 + lane]      = f2bf(nrm[(size_t)ctr*288 + lane]);
            row[SEG0 + 64 + lane] = f2bf(nrm[(size_t)nbr*288 + lane]);
        }
        {
            const float* lr = lat + (size_t)ae * 128;
            row[SEGL + lane]      = f2bf(lr[lane]);
            row[SEGL + 64 + lane] = f2bf(lr[lane + 64]);
        }

        // --- local frame D1 rows (u, n, v) + analytic l=2 Wigner ---
        float vx = evec[3*ae], vy = evec[3*ae+1], vz = evec[3*ae+2];
        float nnv = fmaxf(sqrtf(vx*vx + vy*vy + vz*vz), 1e-9f);
        float nx = vx/nnv, ny = vy/nnv, nz = vz/nnv;
        float ax, az;
        if (fabsf(nx) < 0.9f) { ax = 1.f; az = 0.f; } else { ax = 0.f; az = 1.f; }
        float adn = ax*nx + az*nz;
        float ux = ax - adn*nx, uy = -adn*ny, uz = az - adn*nz;
        float un = fmaxf(sqrtf(ux*ux + uy*uy + uz*uz), 1e-9f);
        ux /= un; uy /= un; uz /= un;
        float wx = uy*nz - uz*ny, wy = uz*nx - ux*nz, wz = ux*ny - uy*nx;

        float d2[5][5];
        d2[0][0] = wz*ux + uz*wx;  d2[0][1] = wx*uy + ux*wy;  d2[0][2] = SQ3F*wy*uy;
        d2[0][3] = wy*uz + uy*wz;  d2[0][4] = wz*uz - wx*ux;
        d2[1][0] = uz*nx + nz*ux;  d2[1][1] = ux*ny + nx*uy;  d2[1][2] = SQ3F*uy*ny;
        d2[1][3] = uy*nz + ny*uz;  d2[1][4] = uz*nz - ux*nx;
        d2[2][0] = SQ3F*nz*nx;     d2[2][1] = SQ3F*nx*ny;     d2[2][2] = 1.5f*ny*ny - 0.5f;
        d2[2][3] = SQ3F*ny*nz;     d2[2][4] = 0.5f*SQ3F*(nz*nz - nx*nx);
        d2[3][0] = nz*wx + wz*nx;  d2[3][1] = nx*wy + wx*ny;  d2[3][2] = SQ3F*ny*wy;
        d2[3][3] = ny*wz + wy*nz;  d2[3][4] = nz*wz - nx*wx;
        d2[4][0] = wz*wx - uz*ux;  d2[4][1] = wx*wy - ux*uy;  d2[4][2] = 0.5f*SQ3F*(wy*wy - uy*uy);
        d2[4][3] = wy*wz - uy*uz;  d2[4][4] = 0.5f*(wz*wz - uz*uz - wx*wx + ux*ux);

        if (lane == 0) {
            sD1[e][0] = ux; sD1[e][1] = uy; sD1[e][2] = uz;
            sD1[e][3] = nx; sD1[e][4] = ny; sD1[e][5] = nz;
            sD1[e][6] = wx; sD1[e][7] = wy; sD1[e][8] = wz;
#pragma unroll
            for (int n = 0; n < 5; ++n)
#pragma unroll
                for (int m = 0; m < 5; ++m) sD2[e][5*n + m] = d2[n][m];
        }

        asm volatile("s_waitcnt lgkmcnt(0)" ::: "memory");

        // --- rotate l=1/l=2 channels into bf16 staged layout ---
#pragma unroll
        for (int half = 0; half < 2; ++half) {
            const int cc = lane + 64*half;
            if (cc < 96) {
                float x1v[3], x2v[5];
                if (cc < 32) {
                    const float* b = nrm + (size_t)ctr * 288;
#pragma unroll
                    for (int m = 0; m < 3; ++m) x1v[m] = b[32 + 32*m + cc];
#pragma unroll
                    for (int m = 0; m < 5; ++m) x2v[m] = b[128 + 32*m + cc];
                } else if (cc < 64) {
                    const int c = cc - 32;
#pragma unroll
                    for (int m = 0; m < 3; ++m) x1v[m] = sE[32 + 32*m + c];
#pragma unroll
                    for (int m = 0; m < 5; ++m) x2v[m] = sE[128 + 32*m + c];
                } else {
                    const float* b = nrm + (size_t)nbr * 288;
                    const int c = cc - 64;
#pragma unroll
                    for (int m = 0; m < 3; ++m) x1v[m] = b[32 + 32*m + c];
#pragma unroll
                    for (int m = 0; m < 5; ++m) x2v[m] = b[128 + 32*m + c];
                }
                float r0 = ux*x1v[0] + uy*x1v[1] + uz*x1v[2];
                float r1 = nx*x1v[0] + ny*x1v[1] + nz*x1v[2];
                float r2 = wx*x1v[0] + wy*x1v[1] + wz*x1v[2];
                float t[5];
#pragma unroll
                for (int m = 0; m < 5; ++m)
                    t[m] = d2[m][0]*x2v[0] + d2[m][1]*x2v[1] + d2[m][2]*x2v[2]
                         + d2[m][3]*x2v[3] + d2[m][4]*x2v[4];
                row[SEG0 + 96  + cc] = f2bf(r1);
                row[SEG0 + 192 + cc] = f2bf(t[2]);
                row[SEGP1 + cc]      = f2bf(r2);
                row[SEGP1 + 96 + cc] = f2bf(t[3]);
                row[SEGM1 + cc]      = f2bf(r0);
                row[SEGM1 + 96 + cc] = f2bf(t[1]);
                row[SEGP2 + cc]      = f2bf(t[4]);
                row[SEGM2 + cc]      = f2bf(t[0]);
            }
        }
    }
    __syncthreads();

    // ---------------- MFMA GEMM phase: 28 tiles across 4 waves ----------------
    // A rows 8..15 duplicate rows 0..7 (only 8 edges); their outputs are discarded.
    for (int t = wv; t < 28; t += 4) {
        int kbase, nch, yoff, pbase; float scale;
        if (t < 10)      { kbase = SEG0;  nch = 9;  yoff = t*16;          scale = S0F; pbase = PK1 + t*9*512; }
        else if (t < 18) { kbase = SEGP1; nch = 12; yoff = 160+(t-10)*16; scale = S1F; pbase = PK2 + (t-10)*12*512; }
        else if (t < 22) { kbase = SEGP2; nch = 6;  yoff = 288+(t-18)*16; scale = S2F; pbase = PK3 + (t-18)*6*512; }
        else             { kbase = SEGL;  nch = 4;  yoff = 352+(t-22)*16; scale = SEF; pbase = PK4 + (t-22)*4*512; }
        f32x4 acc = {0.f, 0.f, 0.f, 0.f};
        const ushort* pa = sA + (lane & 7) * AST + kbase + (lane >> 4) * 8;
        const ushort* pb = pk + pbase + lane * 8;
        for (int ch = 0; ch < nch; ++ch) {
            bf16x8 a = *reinterpret_cast<const bf16x8*>(pa + ch * 32);
            bf16x8 b = *reinterpret_cast<const bf16x8*>(pb + ch * 512);
            acc = __builtin_amdgcn_mfma_f32_16x16x32_bf16(a, b, acc, 0, 0, 0);
        }
        const int col = yoff + (lane & 15);
        const int r0 = (lane >> 4) * 4;
        if (r0 < EPB) {
            float bv = (t >= 22) ? benv[col - 352] : 0.f;
#pragma unroll
            for (int j = 0; j < 4; ++j)
                sY[(r0 + j) * YST + col] = acc[j] * scale + bv;
        }
    }
    __syncthreads();

    // ---------------- stage 2a: gates + rotate-back (thread = edge x channel) ----------------
    const int e2 = tid & 7, c = tid >> 3;   // c in 0..31
    const float* yrow = sY + e2 * YST;
    float* sF = reinterpret_cast<float*>(sA) + e2 * 500;  // reuse sA
    {
        float y0v = yrow[Y0o + c];
        float scv = y0v / (1.f + expf(-y0v));
        float gg1 = 1.f / (1.f + expf(-yrow[Y0o + 32 + c]));
        float gg2 = 1.f / (1.f + expf(-yrow[Y0o + 64 + c]));
        float y1n0 = yrow[Y1Mo + c], y1n1 = yrow[Y10o + c], y1n2 = yrow[Y1Po + c];
        float y2n0 = yrow[Y2M2o + c], y2n1 = yrow[Y2M1o + c], y2n2 = yrow[Y20o + c];
        float y2n3 = yrow[Y2P1o + c], y2n4 = yrow[Y2P2o + c];
        sF[c] = scv;
#pragma unroll
        for (int m = 0; m < 3; ++m) {
            float yw = sD1[e2][m]*y1n0 + sD1[e2][3+m]*y1n1 + sD1[e2][6+m]*y1n2;
            sF[32 + 3*c + m] = yw * gg1;
        }
#pragma unroll
        for (int m = 0; m < 5; ++m) {
            float yw = sD2[e2][m]*y2n0 + sD2[e2][5+m]*y2n1 + sD2[e2][10+m]*y2n2
                     + sD2[e2][15+m]*y2n3 + sD2[e2][20+m]*y2n4;
            sF[128 + 5*c + m] = yw * gg2;
        }
    }
    __syncthreads();

    // ---------------- stage 2b: wp projections + env gate + scatter ----------------
    const int d = c;   // 0..31
    float* ob = out + (size_t)sCtr[e2] * 288;
    {
        float acc0 = 0.f;
        for (int cc = 0; cc < 32; ++cc) acc0 += wp0[d*32 + cc] * sF[cc];
        float m0v = (acc0 * SCF + bp0[d]) * yrow[WENVo + d];
        atomicAdd(ob + d, COEFF * m0v);

        float b1[3] = {};
        for (int cc = 0; cc < 32; ++cc) {
            float w = wp1[d*32 + cc];
            b1[0] += w * sF[32 + 3*cc];
            b1[1] += w * sF[32 + 3*cc + 1];
            b1[2] += w * sF[32 + 3*cc + 2];
        }
        float wv1 = yrow[WENVo + 32 + d];
#pragma unroll
        for (int m = 0; m < 3; ++m) atomicAdd(ob + 32 + 3*d + m, COEFF * (b1[m] * SCF * wv1));

        float b2[5] = {};
        for (int cc = 0; cc < 32; ++cc) {
            float w = wp2[d*32 + cc];
            b2[0] += w * sF[128 + 5*cc];
            b2[1] += w * sF[128 + 5*cc + 1];
            b2[2] += w * sF[128 + 5*cc + 2];
            b2[3] += w * sF[128 + 5*cc + 3];
            b2[4] += w * sF[128 + 5*cc + 4];
        }
        float wv2 = yrow[WENVo + 64 + d];
#pragma unroll
        for (int m = 0; m < 5; ++m) atomicAdd(ob + 128 + 5*d + m, COEFF * (b2[m] * SCF * wv2));
    }
}

extern "C" void kernel_launch(void* const* d_in, const int* in_sizes, int n_in,
                              void* d_out, int out_size, void* d_ws, size_t ws_size,
                              hipStream_t stream)
{
    const float* latents = (const float*)d_in[0];
    const float* nf      = (const float*)d_in[1];
    const float* efe     = (const float*)d_in[2];
    const float* evec    = (const float*)d_in[3];
    const int*   eidx    = (const int*)d_in[5];
    const int*   act     = (const int*)d_in[6];
    const float* g0n = (const float*)d_in[7];
    const float* b0n = (const float*)d_in[8];
    const float* g1n = (const float*)d_in[9];
    const float* g2n = (const float*)d_in[10];
    const float* g0e = (const float*)d_in[11];
    const float* b0e = (const float*)d_in[12];
    const float* g1e = (const float*)d_in[13];
    const float* g2e = (const float*)d_in[14];
    const float* w0s = (const float*)d_in[15];
    const float* w01 = (const float*)d_in[16];
    const float* w02 = (const float*)d_in[17];
    const float* wr11 = (const float*)d_in[18];
    const float* wi11 = (const float*)d_in[19];
    const float* wr12 = (const float*)d_in[20];
    const float* wi12 = (const float*)d_in[21];
    const float* wr22 = (const float*)d_in[22];
    const float* wi22 = (const float*)d_in[23];
    const float* wp0 = (const float*)d_in[24];
    const float* bp0 = (const float*)d_in[25];
    const float* wp1 = (const float*)d_in[26];
    const float* wp2 = (const float*)d_in[27];
    const float* wenv = (const float*)d_in[28];
    const float* benv = (const float*)d_in[29];
    float* out = (float*)d_out;
    float* nrm = (float*)d_ws;                         // N*288 f32 = 11.52 MB (planar)
    ushort* pkw = (ushort*)((char*)d_ws + (size_t)NRM_FLOATS * 4);  // 240 KB packed bf16 weights

    pack_k<<<(PKTOT + 255) / 256, 256, 0, stream>>>(w0s, w01, w02, wr11, wi11, wr12, wi12,
                                                    wr22, wi22, wenv, pkw);
    node_norm_k<<<(NN + 3) / 4, 256, 0, stream>>>(nf, g0n, b0n, g1n, g2n, nrm, out);
    edge_k<<<EE / EPB, 256, 0, stream>>>(latents, efe, evec, eidx, act,
        g0e, b0e, g1e, g2e, pkw, wp0, bp0, wp1, wp2, benv, nrm, out);
}